// Round 5
// baseline (134.304 us; speedup 1.0000x reference)
//
#include <hip/hip_runtime.h>

// Loss = mean(0.5*(o-t)^2 * ef(t)) over N = 64*1*512*512 = 2^24 fp32 elements.
// ef(t) = BETA - exp((A-1)*ln(x) - x + BIAS),  x = (t - LOC)/SCALE
// Path model (measured): coherent reads pin ~3.0 TB/s solo (~2.2 under mixed
// load); NT/HBM ~3.7; best mixed (R7) 4.3 TB/s (~31us). tgt is IF$-resident
// across iters (FETCH=64MiB = out only); nt/sc1 do NOT allocate IF$ (R9).
// R8/R9 monolithic asm: 41-46us REGRESSION (16 dests pinned, no compiler
// scheduling). R10 (separate asm nt loads + global vmcnt(0) guard + (256,4)):
// ~34-39us inferred — guards serialize, asm still opaque to waitcnt tracking.
// R11: NO asm. out-loads via __builtin_nontemporal_load (nt bit, fully
// compiler-tracked -> staged waits + free scheduling, the thing that made R7
// fast). tgt rounds 0-5 plain cached (IF$-allocating), rounds 6-7 ALSO nt:
// rebalance f=1/4 of tgt off the slower coherent pipe (48MiB cached / 80MiB
// NT). (256,2). Predict main ~24-29us (wall ~119-125), FETCH +16MiB ->
// ~82MB. Null (wall ~131, FETCH +16MiB) => total request-rate cap, not
// separate pipes -> at mixed-path roofline.
// R12 = R11 resubmitted verbatim (GPU acquisition timeout, never measured).

#define NBLOCKS 2048
#define NTHREADS 256
#define F4_PER_THREAD 8   // 2048*256*8*4 = 2^24 elements exactly

typedef float vf4 __attribute__((ext_vector_type(4)));

__device__ __forceinline__ float ef_term(float o, float y) {
    constexpr float A_M1      = -0.93555708575356741f;  // EST_A - 1
    constexpr float NEG_LOC   =  1.1328205299926424e-27f;
    constexpr float INV_SCALE =  0.65034886603218541f;  // 1/1.5376362609160314
    constexpr float BIAS      = -56.8416699f;
    constexpr float BETA      =  5.0f;

    float x  = (y + NEG_LOC) * INV_SCALE;           // > 0 for y >= 0
    float ex = __expf(fmaf(A_M1, __logf(x), BIAS - x));
    float ef = BETA - ex;                            // == c when y == 0
    float d  = o - y;
    return 0.5f * d * d * ef;
}

__device__ __forceinline__ vf4 ld_nt(const vf4* p) {
    return __builtin_nontemporal_load(p);
}

__device__ __forceinline__ float block_reduce(float acc) {
    #pragma unroll
    for (int off = 32; off > 0; off >>= 1)
        acc += __shfl_down(acc, off, 64);
    __shared__ float wsum[NTHREADS / 64];
    int lane = threadIdx.x & 63;
    int wave = threadIdx.x >> 6;
    if (lane == 0) wsum[wave] = acc;
    __syncthreads();
    float s = 0.f;
    if (threadIdx.x == 0) {
        #pragma unroll
        for (int w = 0; w < NTHREADS / 64; ++w) s += wsum[w];
    }
    return s;  // valid on thread 0 only
}

// Fast path: n == NBLOCKS*NTHREADS*F4_PER_THREAD*4 exactly.
// Round r fully coalesced: float4 index = chunk_base + r*NTHREADS + tid.
// out: nt (HBM stream). tgt rounds 0-5: cached (IF$-resident). tgt rounds
// 6-7: nt (rebalanced onto the NT pipe). All loads compiler-tracked.
__global__ __launch_bounds__(NTHREADS, 2) void ef_loss_partial_fast(
    const float* __restrict__ out, const float* __restrict__ tgt,
    float* __restrict__ partials) {
    const int base = blockIdx.x * (NTHREADS * F4_PER_THREAD) + threadIdx.x;
    const vf4* __restrict__ op = (const vf4*)out;
    const vf4* __restrict__ tp = (const vf4*)tgt;

    vf4 o0 = ld_nt(op + base + 0 * NTHREADS);
    vf4 o1 = ld_nt(op + base + 1 * NTHREADS);
    vf4 o2 = ld_nt(op + base + 2 * NTHREADS);
    vf4 o3 = ld_nt(op + base + 3 * NTHREADS);
    vf4 o4v = ld_nt(op + base + 4 * NTHREADS);
    vf4 o5 = ld_nt(op + base + 5 * NTHREADS);
    vf4 o6 = ld_nt(op + base + 6 * NTHREADS);
    vf4 o7 = ld_nt(op + base + 7 * NTHREADS);

    vf4 t0 = tp[base + 0 * NTHREADS];
    vf4 t1 = tp[base + 1 * NTHREADS];
    vf4 t2 = tp[base + 2 * NTHREADS];
    vf4 t3 = tp[base + 3 * NTHREADS];
    vf4 t4v = tp[base + 4 * NTHREADS];
    vf4 t5 = tp[base + 5 * NTHREADS];
    vf4 t6 = ld_nt(tp + base + 6 * NTHREADS);
    vf4 t7 = ld_nt(tp + base + 7 * NTHREADS);

    float a0 = 0.f, a1 = 0.f, a2 = 0.f, a3 = 0.f;

#define EF_ROUND(ov, tv)                                                    \
    do {                                                                    \
        a0 += ef_term(ov.x, tv.x);                                          \
        a1 += ef_term(ov.y, tv.y);                                          \
        a2 += ef_term(ov.z, tv.z);                                          \
        a3 += ef_term(ov.w, tv.w);                                          \
    } while (0)

    EF_ROUND(o0, t0);
    EF_ROUND(o1, t1);
    EF_ROUND(o2, t2);
    EF_ROUND(o3, t3);
    EF_ROUND(o4v, t4v);
    EF_ROUND(o5, t5);
    EF_ROUND(o6, t6);
    EF_ROUND(o7, t7);
#undef EF_ROUND

    float s = block_reduce((a0 + a1) + (a2 + a3));
    if (threadIdx.x == 0) partials[blockIdx.x] = s;
}

// Generic fallback (any n).
__global__ __launch_bounds__(NTHREADS) void ef_loss_partial_gen(
    const float* __restrict__ out, const float* __restrict__ tgt,
    float* __restrict__ partials, int n) {
    const int idx    = blockIdx.x * blockDim.x + threadIdx.x;
    const int stride = gridDim.x * blockDim.x;
    const int n4     = n >> 2;
    const float4* __restrict__ o4 = (const float4*)out;
    const float4* __restrict__ t4 = (const float4*)tgt;

    float acc = 0.f;
    for (int i = idx; i < n4; i += stride) {
        float4 o = o4[i];
        float4 t = t4[i];
        acc += ef_term(o.x, t.x);
        acc += ef_term(o.y, t.y);
        acc += ef_term(o.z, t.z);
        acc += ef_term(o.w, t.w);
    }
    for (int i = (n4 << 2) + idx; i < n; i += stride)
        acc += ef_term(out[i], tgt[i]);

    float s = block_reduce(acc);
    if (threadIdx.x == 0) partials[blockIdx.x] = s;
}

__global__ __launch_bounds__(NTHREADS) void ef_loss_finalize(
    const float* __restrict__ partials, float* __restrict__ result,
    int nblocks, float inv_n) {
    float acc = 0.f;
    for (int i = threadIdx.x; i < nblocks; i += blockDim.x)
        acc += partials[i];
    float s = block_reduce(acc);
    if (threadIdx.x == 0) result[0] = s * inv_n;
}

extern "C" void kernel_launch(void* const* d_in, const int* in_sizes, int n_in,
                              void* d_out, int out_size, void* d_ws, size_t ws_size,
                              hipStream_t stream) {
    const float* out_p = (const float*)d_in[0];   // "output"
    const float* tgt_p = (const float*)d_in[1];   // "target"
    float* partials = (float*)d_ws;               // NBLOCKS floats = 8 KB
    float* result   = (float*)d_out;
    const int n = in_sizes[0];

    if (n == NBLOCKS * NTHREADS * F4_PER_THREAD * 4) {
        ef_loss_partial_fast<<<NBLOCKS, NTHREADS, 0, stream>>>(out_p, tgt_p, partials);
    } else {
        ef_loss_partial_gen<<<NBLOCKS, NTHREADS, 0, stream>>>(out_p, tgt_p, partials, n);
    }
    ef_loss_finalize<<<1, NTHREADS, 0, stream>>>(partials, result, NBLOCKS,
                                                 1.0f / (float)n);
}